// Round 7
// baseline (171.279 us; speedup 1.0000x reference)
//
#include <hip/hip_runtime.h>
#include <hip/hip_bf16.h>

// Problem constants
#define BB 4
#define NN 4096
#define JSPLIT 8

typedef __attribute__((ext_vector_type(8))) short short8;   // 8 bf16 (4 VGPRs)
typedef __attribute__((ext_vector_type(4))) float f32x4;    // MFMA C/D

// ws layout (float units):
//  qb     bf16 [4][4096][8]                @f 0        (65536 f)
//  kb     bf16 [4][4096][8]                @f 65536    (65536 f)
//  vb     bf16 [4][64][4][2][4][16][8]     @f 131072   (1048576 f)
//         (= [b][jtile][ct][kstep][quad][lane15][jj], B-fragment order)
//  wfragg bf16 [18][64][8]                 @f 1179648  (4608 f)   A-frags of W
//  bias   f32  [144]                       @f 1184256  (144 f)
//  pout   bf16 [8][4][64][4096]            @f 1184400  (4194304 f)
//  pl     f32  [8][4][4096]                @f 5378704  (131072 f)

__device__ __forceinline__ unsigned short f2bf(float f) {        // RN
    unsigned u = __float_as_uint(f);
    return (unsigned short)((u + 0x7FFFu + ((u >> 16) & 1u)) >> 16);
}
__device__ __forceinline__ unsigned short f2bfz(float f) {       // RTZ (cheap)
    return (unsigned short)(__float_as_uint(f) >> 16);
}

// ---------------------------------------------------------------------------
// Kernel 0: bake W (144x64) into bf16 MFMA A-fragments + bias, once.
// grid 36 x 256 = 9216 threads, one W element each (coalesced reads).
// wfragg entry: [(chunk*2+kstep)*64 + quad*16 + (o&15)]*8 + jj,
//   where o=chunk*16+(o&15), c=kstep*32+quad*8+jj.
// ---------------------------------------------------------------------------
__global__ __launch_bounds__(256) void wsetup_kernel(
    const float* __restrict__ Wq, const float* __restrict__ bq,
    const float* __restrict__ Wk, const float* __restrict__ bk,
    const float* __restrict__ Wv, const float* __restrict__ bv,
    const float* __restrict__ W1, const float* __restrict__ b1,
    unsigned short* __restrict__ wfragg, float* __restrict__ bias)
{
    const int f = blockIdx.x * 256 + threadIdx.x;   // 0..9215
    const int o = f >> 6, c = f & 63;
    float wv;
    if (f < 512)        wv = Wq[f];
    else if (f < 1024)  wv = Wk[f - 512];
    else if (f < 5120)  wv = Wv[f - 1024];
    else                wv = W1[f - 5120];
    const int chunk = o >> 4, ks = c >> 5, quad = (c >> 3) & 3, jj = c & 7;
    wfragg[(((chunk * 2 + ks) * 64) + quad * 16 + (o & 15)) * 8 + jj] = f2bf(wv);
    if (blockIdx.x == 0 && threadIdx.x < 144) {
        const int t = threadIdx.x;
        bias[t] = (t < 8) ? bq[t] : (t < 16) ? bk[t - 8]
                : (t < 80) ? bv[t - 16] : b1[t - 80];
    }
}

// ---------------------------------------------------------------------------
// Kernel 1: fused 1x1 convs via MFMA, W-fragments read per-lane from ws.
// grid 1024 = 4 b x 256 n-tiles of 16; block 256.
// ---------------------------------------------------------------------------
__global__ __launch_bounds__(256) void proj_kernel(
    const float* __restrict__ x,
    const unsigned short* __restrict__ wfragg, const float* __restrict__ bias,
    unsigned short* __restrict__ qb, unsigned short* __restrict__ kb,
    unsigned short* __restrict__ vb, float* __restrict__ out)
{
    __shared__ __align__(16) unsigned short xh[16 * 80];  // [n][c] bf16
    __shared__ float bl[144];

    const int tid = threadIdx.x;
    const int blk = blockIdx.x;
    const int b  = blk >> 8;
    const int n0 = (blk & 255) * 16;

    if (tid < 144) bl[tid] = bias[tid];
    #pragma unroll
    for (int e = tid; e < 1024; e += 256) {
        const int c = e >> 4, nl = e & 15;
        xh[nl * 80 + c] = f2bf(x[(b * 64 + c) * NN + n0 + nl]);
    }
    __syncthreads();

    const int w = tid >> 6, lane = tid & 63;
    const int q = lane >> 4, l15 = lane & 15;
    const int n = n0 + l15;

    const short8 xf0 = *(const short8*)&xh[l15 * 80 + q * 8];
    const short8 xf1 = *(const short8*)&xh[l15 * 80 + 32 + q * 8];
    const f32x4 zf = {0.f, 0.f, 0.f, 0.f};

    const int vt = n >> 6, vs = (n >> 5) & 1, vq = (n >> 3) & 3, vjj = n & 7;

    // wave w handles chunks {w, w+4}; wave 0 also chunk 8
    #pragma unroll
    for (int ci = 0; ci < 3; ++ci) {
        if (ci == 2 && w != 0) break;
        const int chunk = (ci == 2) ? 8 : (w + ci * 4);
        const short8 a0 = *(const short8*)&wfragg[((chunk * 2 + 0) * 64 + lane) * 8];
        const short8 a1 = *(const short8*)&wfragg[((chunk * 2 + 1) * 64 + lane) * 8];
        f32x4 d = __builtin_amdgcn_mfma_f32_16x16x32_bf16(a0, xf0, zf, 0, 0, 0);
        d = __builtin_amdgcn_mfma_f32_16x16x32_bf16(a1, xf1, d, 0, 0, 0);
        #pragma unroll
        for (int r = 0; r < 4; ++r) {
            const int o = chunk * 16 + q * 4 + r;
            const float val = d[r] + bl[o];
            if (o < 8) {
                qb[(size_t)(b * NN + n) * 8 + o] = f2bfz(val);
            } else if (o < 16) {
                kb[(size_t)(b * NN + n) * 8 + (o - 8)] = f2bfz(val);
            } else if (o < 80) {
                const int c = o - 16;
                size_t idx = ((((size_t)((b * 64 + vt) * 4 + (c >> 4)) * 2 + vs) * 4 + vq) * 16
                              + (c & 15)) * 8 + vjj;
                vb[idx] = f2bfz(val);
            } else {
                out[(size_t)(b * 64 + (o - 80)) * NN + n] = val;   // x1 fp32 exact
            }
        }
    }
}

// ---------------------------------------------------------------------------
// Kernel 2: MFMA flash attention. grid 2048 = 8 jsplit x 4 b x 64 i-tiles;
// block 256 = 4 fully independent waves (no barriers). V/K per-lane direct
// from global (L2-hot), all 8 V b128 loads hoisted to tile top so their
// latency overlaps the E->exp->LDS-P chain. launch_bounds(256,5): <=102 VGPR,
// 5 blocks/CU, with register room for in-flight loads.
// ---------------------------------------------------------------------------
__global__ __launch_bounds__(256, 5) void attn_kernel(
    const unsigned short* __restrict__ qws,
    const unsigned short* __restrict__ kws,
    const unsigned short* __restrict__ vfrag,
    unsigned short* __restrict__ pout, float* __restrict__ pl)
{
    __shared__ __align__(16) unsigned char smem[4 * 4352];

    const int tid  = threadIdx.x;
    const int w    = tid >> 6;
    const int lane = tid & 63;
    const int q    = lane >> 4;
    const int l15  = lane & 15;

    const int blk = blockIdx.x;       // 0..2047
    const int it  = blk & 63;
    const int b   = (blk >> 6) & 3;
    const int js  = blk >> 8;         // 0..7
    const int i0  = it * 64;

    unsigned short* pw = (unsigned short*)(smem + w * 4352);  // rows: stride 72 shorts
    float*        olds = (float*)(smem + w * 4352);           // [64][17] (epilogue)

    const short8 z8 = {0, 0, 0, 0, 0, 0, 0, 0};
    const f32x4 zf = {0.f, 0.f, 0.f, 0.f};

    // Q A-fragment: quads 1..3 zeroed (K dim padded 8->32)
    short8 qf = *(const short8*)&qws[(size_t)(b * NN + i0 + w * 16 + l15) * 8];
    if (q != 0) qf = z8;

    f32x4 acc[4] = {zf, zf, zf, zf};
    float l4[4] = {0.f, 0.f, 0.f, 0.f};

    const unsigned short* kbase = kws + (size_t)(b * NN + js * 512) * 8;
    const unsigned short* vbase = vfrag + (size_t)(b * 64 + js * 8) * 4096;

    for (int t = 0; t < 8; ++t) {
        const unsigned short* kt = kbase + (size_t)t * 4096;
        const unsigned short* vt = vbase + (size_t)t * 4096;

        // ---- V fragment loads issued first: latency hides behind E phase ----
        short8 v[8];
        #pragma unroll
        for (int u = 0; u < 8; ++u)
            v[u] = *(const short8*)&vt[(u * 64 + lane) * 8];

        // ---- energy: E[i][j] = Q.K^T (K zero-padded 8->32) ----
        #pragma unroll
        for (int jt = 0; jt < 4; ++jt) {
            // q-independent address: lanes q>0 feed k>=8 which multiply qf=0
            const short8 kf = *(const short8*)&kt[(jt * 16 + l15) * 8];
            const f32x4 e = __builtin_amdgcn_mfma_f32_16x16x32_bf16(qf, kf, zf, 0, 0, 0);
            #pragma unroll
            for (int r = 0; r < 4; ++r) {
                const float p = __expf(e[r]);       // row q*4+r, col jt*16+l15
                l4[r] += p;
                pw[(q * 4 + r) * 72 + jt * 16 + l15] = f2bfz(p);
            }
        }
        // ---- P A-fragments (wave-private, ordered by lgkmcnt) ----
        const short8 a0 = *(const short8*)&pw[l15 * 72 + q * 8];
        const short8 a1 = *(const short8*)&pw[l15 * 72 + 32 + q * 8];
        // ---- PV: 8 MFMA on prefetched V ----
        #pragma unroll
        for (int ct = 0; ct < 4; ++ct) {
            acc[ct] = __builtin_amdgcn_mfma_f32_16x16x32_bf16(a0, v[2 * ct + 0], acc[ct], 0, 0, 0);
            acc[ct] = __builtin_amdgcn_mfma_f32_16x16x32_bf16(a1, v[2 * ct + 1], acc[ct], 0, 0, 0);
        }
    }

    // ---- epilogue (wave-private; olds overlaps this wave's own pw only) ----
    const int sb = js * BB + b;
    #pragma unroll
    for (int r = 0; r < 4; ++r) {
        float vv = l4[r];
        vv += __shfl_xor(vv, 1);  vv += __shfl_xor(vv, 2);
        vv += __shfl_xor(vv, 4);  vv += __shfl_xor(vv, 8);
        l4[r] = vv;
    }
    if (l15 == 0) {
        #pragma unroll
        for (int r = 0; r < 4; ++r)
            pl[(size_t)sb * NN + i0 + w * 16 + q * 4 + r] = l4[r];
    }
    #pragma unroll
    for (int ct = 0; ct < 4; ++ct)
        #pragma unroll
        for (int r = 0; r < 4; ++r)
            olds[(ct * 16 + l15) * 17 + q * 4 + r] = acc[ct][r];

    // lane = output channel c; 16 i-values -> bf16, two dwordx4 stores
    const float* orow = olds + lane * 17;
    unsigned short* pb = pout + ((size_t)sb * 64 + lane) * NN + i0 + w * 16;
    uint4 pk[2];
    #pragma unroll
    for (int h = 0; h < 2; ++h) {
        unsigned pv[4];
        #pragma unroll
        for (int u = 0; u < 4; ++u) {
            unsigned lo = __float_as_uint(orow[h * 8 + u * 2 + 0]) >> 16;
            unsigned hi = __float_as_uint(orow[h * 8 + u * 2 + 1]) & 0xFFFF0000u;
            pv[u] = lo | hi;
        }
        pk[h] = make_uint4(pv[0], pv[1], pv[2], pv[3]);
    }
    *(uint4*)&pb[0] = pk[0];
    *(uint4*)&pb[8] = pk[1];
}

// ---------------------------------------------------------------------------
// Kernel 3: reduce 8 j-splits (bf16 partials), normalize, gamma*out + x1
// ---------------------------------------------------------------------------
__global__ __launch_bounds__(256) void final_kernel(
    const unsigned short* __restrict__ pout, const float* __restrict__ pl,
    const float* __restrict__ gamma,
    float* __restrict__ out)
{
    const int gid = blockIdx.x * 256 + threadIdx.x;   // 0..262143 (4-elt groups)
    const int b  = gid >> 16;
    const int c  = (gid >> 10) & 63;
    const int g4 = (gid & 1023) * 4;
    const float g = gamma[0];

    f32x4 s = {0.f, 0.f, 0.f, 0.f};
    f32x4 l = {0.f, 0.f, 0.f, 0.f};
    #pragma unroll
    for (int ss = 0; ss < JSPLIT; ++ss) {
        const ushort4 u = *(const ushort4*)&pout[(((size_t)(ss * BB + b)) * 64 + c) * NN + g4];
        s[0] += __uint_as_float((unsigned)u.x << 16);
        s[1] += __uint_as_float((unsigned)u.y << 16);
        s[2] += __uint_as_float((unsigned)u.z << 16);
        s[3] += __uint_as_float((unsigned)u.w << 16);
        l += *(const f32x4*)&pl[(size_t)(ss * BB + b) * NN + g4];
    }
    const size_t o0 = (size_t)gid * 4;
    f32x4 r = *(const f32x4*)&out[o0];
    #pragma unroll
    for (int u = 0; u < 4; ++u) r[u] += g * (s[u] / l[u]);
    *(f32x4*)&out[o0] = r;
}

// ---------------------------------------------------------------------------
extern "C" void kernel_launch(void* const* d_in, const int* in_sizes, int n_in,
                              void* d_out, int out_size, void* d_ws, size_t ws_size,
                              hipStream_t stream) {
    (void)in_sizes; (void)n_in; (void)out_size; (void)ws_size;
    const float* x  = (const float*)d_in[0];
    const float* Wq = (const float*)d_in[1];
    const float* bq = (const float*)d_in[2];
    const float* Wk = (const float*)d_in[3];
    const float* bk = (const float*)d_in[4];
    const float* Wv = (const float*)d_in[5];
    const float* bv = (const float*)d_in[6];
    const float* W1 = (const float*)d_in[7];
    const float* b1 = (const float*)d_in[8];
    const float* gm = (const float*)d_in[9];
    float* out = (float*)d_out;

    float* ws = (float*)d_ws;
    unsigned short* qb     = (unsigned short*)(ws);             // bf16
    unsigned short* kb     = (unsigned short*)(ws + 65536);     // bf16
    unsigned short* vb     = (unsigned short*)(ws + 131072);    // bf16 B-frags
    unsigned short* wfragg = (unsigned short*)(ws + 1179648);   // bf16 A-frags
    float*          bias   = ws + 1184256;
    unsigned short* pout16 = (unsigned short*)(ws + 1184400);   // bf16 partials
    float*          pl     = ws + 5378704;

    wsetup_kernel<<<36, 256, 0, stream>>>(Wq, bq, Wk, bk, Wv, bv, W1, b1,
                                          wfragg, bias);
    proj_kernel<<<1024, 256, 0, stream>>>(x, wfragg, bias, qb, kb, vb, out);
    attn_kernel<<<2048, 256, 0, stream>>>(qb, kb, vb, pout16, pl);
    final_kernel<<<1024, 256, 0, stream>>>(pout16, pl, gm, out);
}

// Round 9
// 117.408 us; speedup vs baseline: 1.4588x; 1.4588x over previous
//
#include <hip/hip_runtime.h>
#include <hip/hip_bf16.h>

// Problem constants
#define BB 4
#define NN 4096
#define JSPLIT 8
#define LOG2E 1.4426950408889634f

typedef __attribute__((ext_vector_type(8))) short short8;   // 8 bf16 (4 VGPRs)
typedef __attribute__((ext_vector_type(4))) float f32x4;    // MFMA C/D

// ws layout (float units):
//  qb     bf16 [4][4096][8]                @f 0        (65536 f)   (pre-scaled by log2e)
//  kb     bf16 [4][4096][8]                @f 65536    (65536 f)
//  vb     bf16 [4][64][4][2][4][16][8]     @f 131072   (1048576 f)
//         (= [b][jtile][ct][kstep][quad][lane15][jj], B-fragment order)
//  wfragg bf16 [18][64][8]                 @f 1179648  (4608 f)   A-frags of W
//  bias   f32  [144]                       @f 1184256  (144 f)
//  pout   bf16 [8][4][64][4096]            @f 1184400  (4194304 f)
//  pl     f32  [8][4][4096]                @f 5378704  (131072 f)

__device__ __forceinline__ unsigned short f2bf(float f) {        // RN
    unsigned u = __float_as_uint(f);
    return (unsigned short)((u + 0x7FFFu + ((u >> 16) & 1u)) >> 16);
}
__device__ __forceinline__ unsigned short f2bfz(float f) {       // RTZ (cheap)
    return (unsigned short)(__float_as_uint(f) >> 16);
}

// ---------------------------------------------------------------------------
// Kernel 0: bake W (144x64) into bf16 MFMA A-fragments + bias, once.
// grid 36 x 256 = 9216 threads, one W element each (coalesced reads).
// Wq/bq rows are pre-scaled by log2e so attn can use exp2 directly.
// ---------------------------------------------------------------------------
__global__ __launch_bounds__(256) void wsetup_kernel(
    const float* __restrict__ Wq, const float* __restrict__ bq,
    const float* __restrict__ Wk, const float* __restrict__ bk,
    const float* __restrict__ Wv, const float* __restrict__ bv,
    const float* __restrict__ W1, const float* __restrict__ b1,
    unsigned short* __restrict__ wfragg, float* __restrict__ bias)
{
    const int f = blockIdx.x * 256 + threadIdx.x;   // 0..9215
    const int o = f >> 6, c = f & 63;
    float wv;
    if (f < 512)        wv = Wq[f] * LOG2E;
    else if (f < 1024)  wv = Wk[f - 512];
    else if (f < 5120)  wv = Wv[f - 1024];
    else                wv = W1[f - 5120];
    const int chunk = o >> 4, ks = c >> 5, quad = (c >> 3) & 3, jj = c & 7;
    wfragg[(((chunk * 2 + ks) * 64) + quad * 16 + (o & 15)) * 8 + jj] = f2bf(wv);
    if (blockIdx.x == 0 && threadIdx.x < 144) {
        const int t = threadIdx.x;
        bias[t] = (t < 8) ? bq[t] * LOG2E : (t < 16) ? bk[t - 8]
                : (t < 80) ? bv[t - 16] : b1[t - 80];
    }
}

// ---------------------------------------------------------------------------
// Kernel 1: fused 1x1 convs via MFMA, W-fragments read per-lane from ws.
// grid 1024 = 4 b x 256 n-tiles of 16; block 256.
// ---------------------------------------------------------------------------
__global__ __launch_bounds__(256) void proj_kernel(
    const float* __restrict__ x,
    const unsigned short* __restrict__ wfragg, const float* __restrict__ bias,
    unsigned short* __restrict__ qb, unsigned short* __restrict__ kb,
    unsigned short* __restrict__ vb, float* __restrict__ out)
{
    __shared__ __align__(16) unsigned short xh[16 * 80];  // [n][c] bf16
    __shared__ float bl[144];

    const int tid = threadIdx.x;
    const int blk = blockIdx.x;
    const int b  = blk >> 8;
    const int n0 = (blk & 255) * 16;

    if (tid < 144) bl[tid] = bias[tid];
    #pragma unroll
    for (int e = tid; e < 1024; e += 256) {
        const int c = e >> 4, nl = e & 15;
        xh[nl * 80 + c] = f2bf(x[(b * 64 + c) * NN + n0 + nl]);
    }
    __syncthreads();

    const int w = tid >> 6, lane = tid & 63;
    const int q = lane >> 4, l15 = lane & 15;
    const int n = n0 + l15;

    const short8 xf0 = *(const short8*)&xh[l15 * 80 + q * 8];
    const short8 xf1 = *(const short8*)&xh[l15 * 80 + 32 + q * 8];
    const f32x4 zf = {0.f, 0.f, 0.f, 0.f};

    const int vt = n >> 6, vs = (n >> 5) & 1, vq = (n >> 3) & 3, vjj = n & 7;

    // wave w handles chunks {w, w+4}; wave 0 also chunk 8
    #pragma unroll
    for (int ci = 0; ci < 3; ++ci) {
        if (ci == 2 && w != 0) break;
        const int chunk = (ci == 2) ? 8 : (w + ci * 4);
        const short8 a0 = *(const short8*)&wfragg[((chunk * 2 + 0) * 64 + lane) * 8];
        const short8 a1 = *(const short8*)&wfragg[((chunk * 2 + 1) * 64 + lane) * 8];
        f32x4 d = __builtin_amdgcn_mfma_f32_16x16x32_bf16(a0, xf0, zf, 0, 0, 0);
        d = __builtin_amdgcn_mfma_f32_16x16x32_bf16(a1, xf1, d, 0, 0, 0);
        #pragma unroll
        for (int r = 0; r < 4; ++r) {
            const int o = chunk * 16 + q * 4 + r;
            const float val = d[r] + bl[o];
            if (o < 8) {
                qb[(size_t)(b * NN + n) * 8 + o] = f2bfz(val);
            } else if (o < 16) {
                kb[(size_t)(b * NN + n) * 8 + (o - 8)] = f2bfz(val);
            } else if (o < 80) {
                const int c = o - 16;
                size_t idx = ((((size_t)((b * 64 + vt) * 4 + (c >> 4)) * 2 + vs) * 4 + vq) * 16
                              + (c & 15)) * 8 + vjj;
                vb[idx] = f2bfz(val);
            } else {
                out[(size_t)(b * 64 + (o - 80)) * NN + n] = val;   // x1 fp32 exact
            }
        }
    }
}

// ---------------------------------------------------------------------------
// Kernel 2: MFMA flash attention. grid 2048 = 8 jsplit x 4 b x 64 i-tiles;
// block 256 = 4 fully independent waves (no barriers). V/K per-lane direct
// from global, loads INLINE (no prefetch array, no launch_bounds — the
// R4/R5-proven spill-free shape; VGPR=48 -> LDS-limited 9 blocks/CU).
// ---------------------------------------------------------------------------
__global__ void attn_kernel(
    const unsigned short* __restrict__ qws,
    const unsigned short* __restrict__ kws,
    const unsigned short* __restrict__ vfrag,
    unsigned short* __restrict__ pout, float* __restrict__ pl)
{
    __shared__ __align__(16) unsigned char smem[4 * 4352];

    const int tid  = threadIdx.x;
    const int w    = tid >> 6;
    const int lane = tid & 63;
    const int q    = lane >> 4;
    const int l15  = lane & 15;

    const int blk = blockIdx.x;       // 0..2047
    const int it  = blk & 63;
    const int b   = (blk >> 6) & 3;
    const int js  = blk >> 8;         // 0..7
    const int i0  = it * 64;

    unsigned short* pw = (unsigned short*)(smem + w * 4352);  // rows: stride 72 shorts
    float*        olds = (float*)(smem + w * 4352);           // [64][17] (epilogue)

    const short8 z8 = {0, 0, 0, 0, 0, 0, 0, 0};
    const f32x4 zf = {0.f, 0.f, 0.f, 0.f};

    // Q A-fragment (pre-scaled by log2e): quads 1..3 zeroed (K padded 8->32)
    short8 qf = *(const short8*)&qws[(size_t)(b * NN + i0 + w * 16 + l15) * 8];
    if (q != 0) qf = z8;

    f32x4 acc[4] = {zf, zf, zf, zf};
    float l4[4] = {0.f, 0.f, 0.f, 0.f};

    const unsigned short* kbase = kws + (size_t)(b * NN + js * 512) * 8;
    const unsigned short* vbase = vfrag + (size_t)(b * 64 + js * 8) * 4096;

    for (int t = 0; t < 8; ++t) {
        const unsigned short* kt = kbase + (size_t)t * 4096;
        const unsigned short* vt = vbase + (size_t)t * 4096;

        // ---- energy: E[i][j] = Q.K^T (K zero-padded 8->32) ----
        #pragma unroll
        for (int jt = 0; jt < 4; ++jt) {
            // q-independent address: lanes q>0 feed k>=8 which multiply qf=0
            const short8 kf = *(const short8*)&kt[(jt * 16 + l15) * 8];
            const f32x4 e = __builtin_amdgcn_mfma_f32_16x16x32_bf16(qf, kf, zf, 0, 0, 0);
            #pragma unroll
            for (int r = 0; r < 4; ++r) {
                const float p = __builtin_amdgcn_exp2f(e[r]);  // row q*4+r, col jt*16+l15
                l4[r] += p;
                pw[(q * 4 + r) * 72 + jt * 16 + l15] = f2bfz(p);
            }
        }
        // ---- P A-fragments (wave-private, ordered by lgkmcnt) ----
        const short8 a0 = *(const short8*)&pw[l15 * 72 + q * 8];
        const short8 a1 = *(const short8*)&pw[l15 * 72 + 32 + q * 8];
        // ---- PV: inline V fragment loads (L2-hot), 8 MFMA ----
        #pragma unroll
        for (int ct = 0; ct < 4; ++ct) {
            const short8 v0 = *(const short8*)&vt[((ct * 2 + 0) * 64 + lane) * 8];
            const short8 v1 = *(const short8*)&vt[((ct * 2 + 1) * 64 + lane) * 8];
            acc[ct] = __builtin_amdgcn_mfma_f32_16x16x32_bf16(a0, v0, acc[ct], 0, 0, 0);
            acc[ct] = __builtin_amdgcn_mfma_f32_16x16x32_bf16(a1, v1, acc[ct], 0, 0, 0);
        }
    }

    // ---- epilogue (wave-private; olds overlaps this wave's own pw only) ----
    const int sb = js * BB + b;
    #pragma unroll
    for (int r = 0; r < 4; ++r) {
        float vv = l4[r];
        vv += __shfl_xor(vv, 1);  vv += __shfl_xor(vv, 2);
        vv += __shfl_xor(vv, 4);  vv += __shfl_xor(vv, 8);
        l4[r] = vv;
    }
    if (l15 == 0) {
        #pragma unroll
        for (int r = 0; r < 4; ++r)
            pl[(size_t)sb * NN + i0 + w * 16 + q * 4 + r] = l4[r];
    }
    #pragma unroll
    for (int ct = 0; ct < 4; ++ct)
        #pragma unroll
        for (int r = 0; r < 4; ++r)
            olds[(ct * 16 + l15) * 17 + q * 4 + r] = acc[ct][r];

    // lane = output channel c; 16 i-values -> bf16, two dwordx4 stores
    const float* orow = olds + lane * 17;
    unsigned short* pb = pout + ((size_t)sb * 64 + lane) * NN + i0 + w * 16;
    uint4 pk[2];
    #pragma unroll
    for (int h = 0; h < 2; ++h) {
        unsigned pv[4];
        #pragma unroll
        for (int u = 0; u < 4; ++u) {
            unsigned lo = __float_as_uint(orow[h * 8 + u * 2 + 0]) >> 16;
            unsigned hi = __float_as_uint(orow[h * 8 + u * 2 + 1]) & 0xFFFF0000u;
            pv[u] = lo | hi;
        }
        pk[h] = make_uint4(pv[0], pv[1], pv[2], pv[3]);
    }
    *(uint4*)&pb[0] = pk[0];
    *(uint4*)&pb[8] = pk[1];
}

// ---------------------------------------------------------------------------
// Kernel 3: reduce 8 j-splits (bf16 partials), normalize, gamma*out + x1
// ---------------------------------------------------------------------------
__global__ __launch_bounds__(256) void final_kernel(
    const unsigned short* __restrict__ pout, const float* __restrict__ pl,
    const float* __restrict__ gamma,
    float* __restrict__ out)
{
    const int gid = blockIdx.x * 256 + threadIdx.x;   // 0..262143 (4-elt groups)
    const int b  = gid >> 16;
    const int c  = (gid >> 10) & 63;
    const int g4 = (gid & 1023) * 4;
    const float g = gamma[0];

    f32x4 s = {0.f, 0.f, 0.f, 0.f};
    f32x4 l = {0.f, 0.f, 0.f, 0.f};
    #pragma unroll
    for (int ss = 0; ss < JSPLIT; ++ss) {
        const ushort4 u = *(const ushort4*)&pout[(((size_t)(ss * BB + b)) * 64 + c) * NN + g4];
        s[0] += __uint_as_float((unsigned)u.x << 16);
        s[1] += __uint_as_float((unsigned)u.y << 16);
        s[2] += __uint_as_float((unsigned)u.z << 16);
        s[3] += __uint_as_float((unsigned)u.w << 16);
        l += *(const f32x4*)&pl[(size_t)(ss * BB + b) * NN + g4];
    }
    const size_t o0 = (size_t)gid * 4;
    f32x4 r = *(const f32x4*)&out[o0];
    #pragma unroll
    for (int u = 0; u < 4; ++u) r[u] += g * (s[u] / l[u]);
    *(f32x4*)&out[o0] = r;
}

// ---------------------------------------------------------------------------
extern "C" void kernel_launch(void* const* d_in, const int* in_sizes, int n_in,
                              void* d_out, int out_size, void* d_ws, size_t ws_size,
                              hipStream_t stream) {
    (void)in_sizes; (void)n_in; (void)out_size; (void)ws_size;
    const float* x  = (const float*)d_in[0];
    const float* Wq = (const float*)d_in[1];
    const float* bq = (const float*)d_in[2];
    const float* Wk = (const float*)d_in[3];
    const float* bk = (const float*)d_in[4];
    const float* Wv = (const float*)d_in[5];
    const float* bv = (const float*)d_in[6];
    const float* W1 = (const float*)d_in[7];
    const float* b1 = (const float*)d_in[8];
    const float* gm = (const float*)d_in[9];
    float* out = (float*)d_out;

    float* ws = (float*)d_ws;
    unsigned short* qb     = (unsigned short*)(ws);             // bf16
    unsigned short* kb     = (unsigned short*)(ws + 65536);     // bf16
    unsigned short* vb     = (unsigned short*)(ws + 131072);    // bf16 B-frags
    unsigned short* wfragg = (unsigned short*)(ws + 1179648);   // bf16 A-frags
    float*          bias   = ws + 1184256;
    unsigned short* pout16 = (unsigned short*)(ws + 1184400);   // bf16 partials
    float*          pl     = ws + 5378704;

    wsetup_kernel<<<36, 256, 0, stream>>>(Wq, bq, Wk, bk, Wv, bv, W1, b1,
                                          wfragg, bias);
    proj_kernel<<<1024, 256, 0, stream>>>(x, wfragg, bias, qb, kb, vb, out);
    attn_kernel<<<2048, 256, 0, stream>>>(qb, kb, vb, pout16, pl);
    final_kernel<<<1024, 256, 0, stream>>>(pout16, pl, gm, out);
}